// Round 13
// baseline (78.269 us; speedup 1.0000x reference)
//
#include <hip/hip_runtime.h>
#include <hip/hip_fp16.h>
#include <math.h>

#define TWO_PI 6.283185307179586f

// workspace layout (float offsets; E/Z/F regions hold halves)
#define OFF_F    0ull          // frames [be][f][4096] __half   = 4194304 floats
#define OFF_E    4194304ull    // E [be][f][2049] __half2       = 4196352 floats
#define OFF_MAXP 8390656ull    // 512 partial maxima (4 per be)
#define OFF_Z    8391680ull    // Z' [be][f][2048] __half2      = 4194304 floats

__device__ __forceinline__ int swz(int n) { return n ^ ((n >> 5) & 31); }

// position of natural index k after DIF with radices [2,4,4,4,4,4]
__device__ __forceinline__ int permf(int k) {
    return ((k & 1) << 10) | (((k >> 1) & 3) << 8) | (((k >> 3) & 3) << 6)
         | (((k >> 5) & 3) << 4) | (((k >> 7) & 3) << 2) | ((k >> 9) & 3);
}

__device__ __forceinline__ float2 uph(unsigned u) {
    __half2 h = *(__half2*)&u;
    return __half22float2(h);
}
__device__ __forceinline__ unsigned pkh(float x, float y) {
    __half2 h = __floats2half2_rn(x, y);
    return *(unsigned*)&h;
}

__device__ __forceinline__ void r4f_core(float* cr, float* ci, int p0, int p1, int p2, int p3,
                                         float c1, float s1, float c2, float s2, float c3, float s3) {
    float ar = cr[p0], ai = ci[p0];
    float br = cr[p1], bi = ci[p1];
    float crr = cr[p2], cri = ci[p2];
    float drr = cr[p3], dri = ci[p3];
    float u0r = ar + crr, u0i = ai + cri;
    float u1r = ar - crr, u1i = ai - cri;
    float u2r = br + drr, u2i = bi + dri;
    float u3r = br - drr, u3i = bi - dri;
    cr[p0] = u0r + u2r; ci[p0] = u0i + u2i;
    float z1r = u1r + u3i, z1i = u1i - u3r;            // u1 - i*u3
    cr[p1] = z1r * c1 + z1i * s1; ci[p1] = z1i * c1 - z1r * s1;
    float z2r = u0r - u2r, z2i = u0i - u2i;
    cr[p2] = z2r * c2 + z2i * s2; ci[p2] = z2i * c2 - z2r * s2;
    float z3r = u1r - u3i, z3i = u1i + u3r;            // u1 + i*u3
    cr[p3] = z3r * c3 + z3i * s3; ci[p3] = z3i * c3 - z3r * s3;
}

// packed half2 inverse radix-4 core
__device__ __forceinline__ void r4i_pk(unsigned* b, int p0, int p1, int p2, int p3,
                                       float c1, float s1, float c2, float s2, float c3, float s3) {
    float2 z0 = uph(b[p0]), z1 = uph(b[p1]), z2 = uph(b[p2]), z3 = uph(b[p3]);
    float t1r = z1.x * c1 - z1.y * s1, t1i = z1.y * c1 + z1.x * s1;
    float t2r = z2.x * c2 - z2.y * s2, t2i = z2.y * c2 + z2.x * s2;
    float t3r = z3.x * c3 - z3.y * s3, t3i = z3.y * c3 + z3.x * s3;
    float u0r = z0.x + t2r, u0i = z0.y + t2i;
    float u1r = z0.x - t2r, u1i = z0.y - t2i;
    float u2r = t1r + t3r, u2i = t1i + t3i;
    float u3r = t1r - t3r, u3i = t1i - t3i;
    b[p0] = pkh(u0r + u2r, u0i + u2i);
    b[p1] = pkh(u1r - u3i, u1i + u3r);                 // u1 + i*u3
    b[p2] = pkh(u0r - u2r, u0i - u2i);
    b[p3] = pkh(u1r + u3i, u1i - u3r);                 // u1 - i*u3
}

// forward: one radix-4 stage over 4 f32 buffers with 1024 threads
#define STAGE4X(CORE, JEXPR, H, ANGEXPR)                                       \
    {                                                                          \
        _Pragma("unroll")                                                      \
        for (int half_ = 0; half_ < 2; ++half_) {                              \
            int b_ = tid + half_ * 1024;                                       \
            int i_ = b_ & 511;                                                 \
            float* cr_ = B + (b_ >> 9) * 4096;                                 \
            float* ci_ = cr_ + 2048;                                           \
            int j_ = (JEXPR);                                                  \
            int p0 = swz(j_), p1 = swz(j_ + (H)), p2 = swz(j_ + 2 * (H)),      \
                p3 = swz(j_ + 3 * (H));                                        \
            float s1, c1; __sincosf((ANGEXPR), &s1, &c1);                      \
            float c2 = c1 * c1 - s1 * s1, s2 = 2.f * c1 * s1;                  \
            float c3 = c1 * c2 - s1 * s2, s3 = s1 * c2 + c1 * s2;              \
            CORE(cr_, ci_, p0, p1, p2, p3, c1, s1, c2, s2, c3, s3);            \
        }                                                                      \
    }                                                                          \
    __syncthreads();

// inverse: one radix-4 stage over 4 packed buffers with 1024 threads
#define STAGE4P(JEXPR, H, ANGEXPR)                                             \
    {                                                                          \
        _Pragma("unroll")                                                      \
        for (int half_ = 0; half_ < 2; ++half_) {                              \
            int b_ = tid + half_ * 1024;                                       \
            int i_ = b_ & 511;                                                 \
            unsigned* bb_ = B2 + (b_ >> 9) * 2048;                             \
            int j_ = (JEXPR);                                                  \
            int p0 = swz(j_), p1 = swz(j_ + (H)), p2 = swz(j_ + 2 * (H)),      \
                p3 = swz(j_ + 3 * (H));                                        \
            float s1, c1; __sincosf((ANGEXPR), &s1, &c1);                      \
            float c2 = c1 * c1 - s1 * s1, s2 = 2.f * c1 * s1;                  \
            float c3 = c1 * c2 - s1 * s2, s3 = s1 * c2 + c1 * s2;              \
            r4i_pk(bb_, p0, p1, p2, p3, c1, s1, c2, s2, c3, s3);               \
        }                                                                      \
    }                                                                          \
    __syncthreads();

// ---- fused: energy + in-register radix-2 + 4x forward FFT + per-quarter tf max
__global__ __launch_bounds__(1024, 8) void k_fwd(const float* __restrict__ env,
                                                 const float* __restrict__ noise,
                                                 const float* __restrict__ tf,
                                                 float* __restrict__ ws) {
    __shared__ float B[16384];   // 4 FFTs x (cr[2048], ci[2048]) = 64 KB
    int tid = threadIdx.x;
    int id = blockIdx.x;
    int xcd = id & 7, slot = id >> 3;
    int be = xcd * 16 + (slot >> 2);
    int fg = slot & 3;                       // f = fg*4 .. fg*4+3
    const float4* env4 = (const float4*)env;
    const float4* noi4 = (const float4*)noise;
    size_t base = (size_t)be * 16384 + fg;

    // thread t owns complexes t and t+1024: samples {2t,2t+1, 2t+2048,2t+2049}.
    // energy + radix-2 (h=1024) butterfly in registers, then scatter.
    {
        float4 ea0 = env4[base + (size_t)(2 * tid) * 4];
        float4 ea1 = env4[base + (size_t)(2 * tid + 1) * 4];
        float4 eb0 = env4[base + (size_t)(2 * tid + 2048) * 4];
        float4 eb1 = env4[base + (size_t)(2 * tid + 2049) * 4];
        float4 za0 = noi4[base + (size_t)(2 * tid) * 4];
        float4 za1 = noi4[base + (size_t)(2 * tid + 1) * 4];
        float4 zb0 = noi4[base + (size_t)(2 * tid + 2048) * 4];
        float4 zb1 = noi4[base + (size_t)(2 * tid + 2049) * 4];
        float4 A0 = make_float4(ea0.x * (za0.x * 2.f - 1.f), ea0.y * (za0.y * 2.f - 1.f),
                                ea0.z * (za0.z * 2.f - 1.f), ea0.w * (za0.w * 2.f - 1.f));
        float4 A1 = make_float4(ea1.x * (za1.x * 2.f - 1.f), ea1.y * (za1.y * 2.f - 1.f),
                                ea1.z * (za1.z * 2.f - 1.f), ea1.w * (za1.w * 2.f - 1.f));
        float4 B0 = make_float4(eb0.x * (zb0.x * 2.f - 1.f), eb0.y * (zb0.y * 2.f - 1.f),
                                eb0.z * (zb0.z * 2.f - 1.f), eb0.w * (zb0.w * 2.f - 1.f));
        float4 B1 = make_float4(eb1.x * (zb1.x * 2.f - 1.f), eb1.y * (zb1.y * 2.f - 1.f),
                                eb1.z * (zb1.z * 2.f - 1.f), eb1.w * (zb1.w * 2.f - 1.f));
        const float* A0v = (const float*)&A0;
        const float* A1v = (const float*)&A1;
        const float* B0v = (const float*)&B0;
        const float* B1v = (const float*)&B1;
        float s, c; __sincosf((float)tid * (TWO_PI / 2048.0f), &s, &c);
        int pj = swz(tid), pjb = swz(tid + 1024);
#pragma unroll
        for (int j4 = 0; j4 < 4; ++j4) {
            float xr = A0v[j4], xi = A1v[j4];
            float yr = B0v[j4], yi = B1v[j4];
            float ar = xr + yr, ai = xi + yi;
            float dr = xr - yr, di = xi - yi;
            float* cr = B + j4 * 4096;
            float* ci = cr + 2048;
            cr[pj] = ar; ci[pj] = ai;
            cr[pjb] = dr * c + di * s;
            ci[pjb] = di * c - dr * s;
        }
    }
    __syncthreads();
    STAGE4X(r4f_core, (i_ >> 8) * 1024 + (i_ & 255), 256, (float)(i_ & 255) * (TWO_PI / 1024.0f));
    STAGE4X(r4f_core, (i_ >> 6) * 256 + (i_ & 63), 64, (float)(i_ & 63) * (TWO_PI / 256.0f));
    STAGE4X(r4f_core, (i_ & 31) * 64 + (i_ >> 5), 16, (float)(i_ >> 5) * (TWO_PI / 64.0f));
    STAGE4X(r4f_core, (i_ & 127) * 16 + (i_ >> 7), 4, (float)(i_ >> 7) * (TWO_PI / 16.0f));
    STAGE4X(r4f_core, i_ * 4, 1, 0.0f);
    // rfft unpack -> E (half2), indices/twiddles shared across the 4 buffers
    __half2* Ebase = (__half2*)(ws + OFF_E) + (size_t)(be * 16 + fg * 4) * 2049;
    for (int k = tid; k <= 1024; k += 1024) {
        int pk = swz(permf(k));
        int pm = swz(permf((2048 - k) & 2047));
        float s4, c4; __sincosf((float)k * (TWO_PI / 4096.0f), &s4, &c4);
#pragma unroll
        for (int j4 = 0; j4 < 4; ++j4) {
            float* cr = B + j4 * 4096;
            float* ci = cr + 2048;
            float zkr = cr[pk], zki = ci[pk], zmr = cr[pm], zmi = ci[pm];
            float xer = 0.5f * (zkr + zmr), xei = 0.5f * (zki - zmi);
            float xor_ = 0.5f * (zki + zmi), xoi = 0.5f * (zmr - zkr);
            float wr = xor_ * c4 + xoi * s4;
            float wi = xoi * c4 - xor_ * s4;
            __half2* Eg = Ebase + (size_t)j4 * 2049;
            Eg[k] = __floats2half2_rn(xer + wr, xei + wi);
            Eg[2048 - k] = __floats2half2_rn(xer - wr, wi - xei);
        }
    }
    __syncthreads();
    // tf max over this block's bin quarter (reuses B)
    const float4* ab4 = (const float4*)(tf + (size_t)be * 65568);
    int b0 = fg * 513;
    int nb = (fg == 3) ? 510 : 513;          // 3*513 + 510 = 2049 bins
    float mx = 0.f;
    for (int u = tid; u < nb * 4; u += 1024) {
        int g = u >> 2, e = u & 3;
        int bin = b0 + g;
        float4 A = ab4[bin * 8 + e];
        float4 Bv = ab4[bin * 8 + e + 4];
        mx = fmaxf(mx, fmaxf(fmaxf(A.x * A.x + Bv.x * Bv.x, A.y * A.y + Bv.y * Bv.y),
                             fmaxf(A.z * A.z + Bv.z * Bv.z, A.w * A.w + Bv.w * Bv.w)));
    }
    B[tid] = mx;
    __syncthreads();
    for (int s = 512; s > 0; s >>= 1) {
        if (tid < s) B[tid] = fmaxf(B[tid], B[tid + s]);
        __syncthreads();
    }
    if (tid == 0) ws[OFF_MAXP + be * 4 + fg] = B[0];
}

// ---- per-bin recurrence on pair (k, 2048-k) + fused irfft pre-pack -> Z' (half2)
__global__ __launch_bounds__(256) void k_recur(const float* __restrict__ tf,
                                               float* __restrict__ ws) {
    __shared__ float sm2lo[256 * 17], simlo[256 * 17];
    __shared__ float sm2hi[256 * 17], simhi[256 * 17];
    int tid = threadIdx.x;
    int be = blockIdx.y;
    int k0 = blockIdx.x << 8;          // 0,256,512,768
    int hi0 = 1793 - k0;               // hi bins [hi0, hi0+255]
    const float* tfb = tf + (size_t)be * 65568;
    const float4* ab4 = (const float4*)tfb;
    const float4* im4 = (const float4*)(tfb + 32784);

    for (int u = tid; u < 2048; u += 256) {
        int half = u >> 10, v = u & 1023;
        int g = v >> 2, e = v & 3;
        int bin = half ? (hi0 + g) : (k0 + g);
        float4 A = ab4[bin * 8 + e];
        float4 Bv = ab4[bin * 8 + e + 4];
        float4 I = im4[bin * 4 + e];
        int o = g * 17 + e * 4;
        float* sm = half ? sm2hi : sm2lo;
        float* si = half ? simhi : simlo;
        sm[o + 0] = A.x * A.x + Bv.x * Bv.x;
        sm[o + 1] = A.y * A.y + Bv.y * Bv.y;
        sm[o + 2] = A.z * A.z + Bv.z * Bv.z;
        sm[o + 3] = A.w * A.w + Bv.w * Bv.w;
        si[o + 0] = I.x; si[o + 1] = I.y; si[o + 2] = I.z; si[o + 3] = I.w;
    }
    __syncthreads();

    int k = k0 + tid;
    int m = 2048 - k;
    int rhi = 255 - tid;
    const float* mp = ws + OFF_MAXP + be * 4;
    float m2x = fmaxf(fmaxf(mp[0], mp[1]), fmaxf(mp[2], mp[3]));
    float rden = 1.0f / (sqrtf(m2x) + 1e-8f);
    const __half2* Eb = (const __half2*)(ws + OFF_E) + (size_t)be * 16 * 2049;
    __half2* Zb = (__half2*)(ws + OFF_Z) + (size_t)be * 16 * 2048;
    float2 evlo[16], evhi[16];
#pragma unroll
    for (int f = 0; f < 16; ++f) {
        evlo[f] = __half22float2(Eb[(size_t)f * 2049 + k]);
        evhi[f] = __half22float2(Eb[(size_t)f * 2049 + m]);
    }
    float ym = (k == 0) ? 0.0f : 1.0f;
    float s4, c4; __sincosf((float)k * (TWO_PI / 4096.0f), &s4, &c4);
    const float SCL = 1.0f / 2048.0f;
    float srl = 0.f, sil = 0.f, srh = 0.f, sih = 0.f;
#pragma unroll
    for (int f = 0; f < 16; ++f) {
        float mh = sqrtf(sm2lo[tid * 17 + f]) * rden;
        float ph = atan2f(simlo[tid * 17 + f], mh) * 3.14159265358979f;
        float sp, cp; __sincosf(ph, &sp, &cp);
        float Tr = mh * cp, Ti = mh * sp;
        sil *= ym;
        srl += evlo[f].x; sil += evlo[f].y;
        float nr = srl * Tr - sil * Ti;
        sil = srl * Ti + sil * Tr; srl = nr;
        float mh2 = sqrtf(sm2hi[rhi * 17 + f]) * rden;
        float ph2 = atan2f(simhi[rhi * 17 + f], mh2) * 3.14159265358979f;
        float sp2, cp2; __sincosf(ph2, &sp2, &cp2);
        float Tr2 = mh2 * cp2, Ti2 = mh2 * sp2;
        sih *= ym;
        srh += evhi[f].x; sih += evhi[f].y;
        float nr2 = srh * Tr2 - sih * Ti2;
        sih = srh * Ti2 + sih * Tr2; srh = nr2;
        __half2* Zf = Zb + (size_t)f * 2048;
        if (k == 0) {
            float y0 = srl * SCL, yn = srh * SCL;
            Zf[0] = __floats2half2_rn(0.5f * (y0 + yn), 0.5f * (y0 - yn));
        } else {
            float ykr = srl * SCL, yki = sil * SCL;
            float ymr = srh * SCL, ymi = sih * SCL;
            float er = 0.5f * (ykr + ymr), ei = 0.5f * (yki - ymi);
            float dr = ykr - ymr, di = yki + ymi;
            float orr = 0.5f * (dr * c4 - di * s4);
            float oi = 0.5f * (dr * s4 + di * c4);
            Zf[k] = __floats2half2_rn(er - oi, ei + orr);
            Zf[m] = __floats2half2_rn(er + oi, orr - ei);
        }
    }
    if (k0 == 0 && tid == 0) {   // bin 1024 (self-paired)
        float sr = 0.f, si = 0.f;
#pragma unroll
        for (int f = 0; f < 16; ++f) {
            float a = tfb[1024 * 32 + f];
            float b = tfb[1024 * 32 + 16 + f];
            float im = tfb[32784 + 1024 * 16 + f];
            float mh = sqrtf(a * a + b * b) * rden;
            float ph = atan2f(im, mh) * 3.14159265358979f;
            float sp, cp; __sincosf(ph, &sp, &cp);
            float Tr = mh * cp, Ti = mh * sp;
            float2 e = __half22float2(Eb[(size_t)f * 2049 + 1024]);
            sr += e.x; si += e.y;
            float nr = sr * Tr - si * Ti;
            si = sr * Ti + si * Tr; sr = nr;
            Zb[(size_t)f * 2048 + 1024] = __floats2half2_rn(sr * SCL, -si * SCL);
        }
    }
}

// ---- inverse FFT: 4 frames per block, packed half2 LDS, merged final radix-2
__global__ __launch_bounds__(1024, 8) void k_fft_inv(float* __restrict__ ws) {
    __shared__ unsigned B2[8192];   // 4 FFTs x 2048 packed half2 = 32 KB
    int tid = threadIdx.x;
    int be = blockIdx.x >> 2, fg = blockIdx.x & 3;
    const __half2* Zbase = (const __half2*)(ws + OFF_Z) + (size_t)(be * 16 + fg * 4) * 2048;
    {
        int n0 = tid * 2;
        int p0 = swz(permf(n0)), p1 = swz(permf(n0 + 1));
#pragma unroll
        for (int j4 = 0; j4 < 4; ++j4) {
            uint2 raw = ((const uint2*)(Zbase + (size_t)j4 * 2048))[tid];
            unsigned* bb = B2 + j4 * 2048;
            bb[p0] = raw.x;
            bb[p1] = raw.y;
        }
    }
    __syncthreads();
    STAGE4P(i_ * 4, 1, 0.0f);
    STAGE4P((i_ & 127) * 16 + (i_ >> 7), 4, (float)(i_ >> 7) * (TWO_PI / 16.0f));
    STAGE4P((i_ & 31) * 64 + (i_ >> 5), 16, (float)(i_ >> 5) * (TWO_PI / 64.0f));
    STAGE4P((i_ >> 6) * 256 + (i_ & 63), 64, (float)(i_ & 63) * (TWO_PI / 256.0f));
    STAGE4P((i_ >> 8) * 1024 + (i_ & 255), 256, (float)(i_ & 255) * (TWO_PI / 1024.0f));
    // merged radix-2 (h=1024) + F writeback
    {
        int sj = swz(tid), sjb = swz(tid + 1024);
        float s, c; __sincosf((float)tid * (TWO_PI / 2048.0f), &s, &c);
        __half2* Fbase = (__half2*)(ws + OFF_F) + (size_t)(be * 16 + fg * 4) * 2048;
#pragma unroll
        for (int j4 = 0; j4 < 4; ++j4) {
            unsigned* bb = B2 + j4 * 2048;
            float2 a = uph(bb[sj]);
            float2 b = uph(bb[sjb]);
            float tr = b.x * c - b.y * s, ti2 = b.x * s + b.y * c;
            __half2* Fg = Fbase + (size_t)j4 * 2048;
            Fg[tid] = __floats2half2_rn(a.x + tr, a.y + ti2);
            Fg[tid + 1024] = __floats2half2_rn(a.x - tr, a.y - ti2);
        }
    }
}

// ---- gather + fused overlap-add (F half in, f32 out)
__global__ __launch_bounds__(256) void k_segment(const float* __restrict__ ws,
                                                 const int* __restrict__ indices,
                                                 float* __restrict__ out) {
    __shared__ int ste[16];
    int tid = threadIdx.x;
    int b = blockIdx.y;
    if (tid < 16) ste[tid] = indices[b * 16 + tid] * 256;
    __syncthreads();
    int g = blockIdx.x * 256 + tid;
    int t = g << 2;
    const __half* F = (const __half*)(ws + OFF_F);
    float4 acc = make_float4(0.f, 0.f, 0.f, 0.f);
#pragma unroll
    for (int e = 0; e < 16; ++e) {
        int te = ste[e];
        if (t >= te) {
            int d = t - te;
            int j = d >> 11, r = d & 2047;
            size_t base = (size_t)(b * 16 + e) * 65536;
            uint2 raw = *(const uint2*)(F + base + j * 4096 + r);
            float2 a0 = __half22float2(*(const __half2*)&raw.x);
            float2 a1 = __half22float2(*(const __half2*)&raw.y);
            acc.x += a0.x; acc.y += a0.y; acc.z += a1.x; acc.w += a1.y;
            if (j >= 1) {
                uint2 rw2 = *(const uint2*)(F + base + (j - 1) * 4096 + 2048 + r);
                float2 b0 = __half22float2(*(const __half2*)&rw2.x);
                float2 b1 = __half22float2(*(const __half2*)&rw2.y);
                acc.x += b0.x; acc.y += b0.y; acc.z += b1.x; acc.w += b1.y;
            }
        }
    }
    ((float4*)out)[(size_t)b * 8192 + g] = acc;
}

extern "C" void kernel_launch(void* const* d_in, const int* in_sizes, int n_in,
                              void* d_out, int out_size, void* d_ws, size_t ws_size,
                              hipStream_t stream) {
    const float* env = (const float*)d_in[0];
    const float* tf = (const float*)d_in[1];
    const float* noise = (const float*)d_in[2];
    const int* indices = (const int*)d_in[3];
    float* ws = (float*)d_ws;
    float* out = (float*)d_out;

    k_fwd<<<dim3(512), dim3(1024), 0, stream>>>(env, noise, tf, ws);
    k_recur<<<dim3(4, 128), dim3(256), 0, stream>>>(tf, ws);
    k_fft_inv<<<dim3(512), dim3(1024), 0, stream>>>(ws);
    k_segment<<<dim3(32, 8), dim3(256), 0, stream>>>(ws, indices, out);
}

// Round 14
// 77.600 us; speedup vs baseline: 1.0086x; 1.0086x over previous
//
#include <hip/hip_runtime.h>
#include <hip/hip_fp16.h>
#include <math.h>

#define TWO_PI 6.283185307179586f

// workspace layout (float offsets; E/Z/F regions hold halves)
#define OFF_F    0ull          // frames [be][f][4096] __half   = 4194304 floats
#define OFF_E    4194304ull    // E [be][f][2049] __half2       = 4196352 floats
#define OFF_MAXP 8390656ull    // 512 partial maxima (4 per be)
#define OFF_Z    8391680ull    // Z' [be][f][2048] __half2      = 4194304 floats

__device__ __forceinline__ int swz(int n) { return n ^ ((n >> 5) & 31); }

// position of natural index k after DIF with radices [2,4,4,4,4,4]
__device__ __forceinline__ int permf(int k) {
    return ((k & 1) << 10) | (((k >> 1) & 3) << 8) | (((k >> 3) & 3) << 6)
         | (((k >> 5) & 3) << 4) | (((k >> 7) & 3) << 2) | ((k >> 9) & 3);
}

__device__ __forceinline__ float2 uph(unsigned u) {
    __half2 h = *(__half2*)&u;
    return __half22float2(h);
}
__device__ __forceinline__ unsigned pkh(float x, float y) {
    __half2 h = __floats2half2_rn(x, y);
    return *(unsigned*)&h;
}

// packed half2 forward radix-4 core (DIF, twiddles e^{-i})
__device__ __forceinline__ void r4f_pk(unsigned* b, int p0, int p1, int p2, int p3,
                                       float c1, float s1, float c2, float s2, float c3, float s3) {
    float2 A = uph(b[p0]), Bv = uph(b[p1]), C = uph(b[p2]), D = uph(b[p3]);
    float u0r = A.x + C.x, u0i = A.y + C.y;
    float u1r = A.x - C.x, u1i = A.y - C.y;
    float u2r = Bv.x + D.x, u2i = Bv.y + D.y;
    float u3r = Bv.x - D.x, u3i = Bv.y - D.y;
    b[p0] = pkh(u0r + u2r, u0i + u2i);
    float z1r = u1r + u3i, z1i = u1i - u3r;            // u1 - i*u3
    b[p1] = pkh(z1r * c1 + z1i * s1, z1i * c1 - z1r * s1);
    float z2r = u0r - u2r, z2i = u0i - u2i;
    b[p2] = pkh(z2r * c2 + z2i * s2, z2i * c2 - z2r * s2);
    float z3r = u1r - u3i, z3i = u1i + u3r;            // u1 + i*u3
    b[p3] = pkh(z3r * c3 + z3i * s3, z3i * c3 - z3r * s3);
}

// packed half2 inverse radix-4 core
__device__ __forceinline__ void r4i_pk(unsigned* b, int p0, int p1, int p2, int p3,
                                       float c1, float s1, float c2, float s2, float c3, float s3) {
    float2 z0 = uph(b[p0]), z1 = uph(b[p1]), z2 = uph(b[p2]), z3 = uph(b[p3]);
    float t1r = z1.x * c1 - z1.y * s1, t1i = z1.y * c1 + z1.x * s1;
    float t2r = z2.x * c2 - z2.y * s2, t2i = z2.y * c2 + z2.x * s2;
    float t3r = z3.x * c3 - z3.y * s3, t3i = z3.y * c3 + z3.x * s3;
    float u0r = z0.x + t2r, u0i = z0.y + t2i;
    float u1r = z0.x - t2r, u1i = z0.y - t2i;
    float u2r = t1r + t3r, u2i = t1i + t3i;
    float u3r = t1r - t3r, u3i = t1i - t3i;
    b[p0] = pkh(u0r + u2r, u0i + u2i);
    b[p1] = pkh(u1r - u3i, u1i + u3r);                 // u1 + i*u3
    b[p2] = pkh(u0r - u2r, u0i - u2i);
    b[p3] = pkh(u1r + u3i, u1i - u3r);                 // u1 - i*u3
}

// one radix-4 stage over 4 packed buffers with 1024 threads
#define STAGE4P(CORE, JEXPR, H, ANGEXPR)                                       \
    {                                                                          \
        _Pragma("unroll")                                                      \
        for (int half_ = 0; half_ < 2; ++half_) {                              \
            int b_ = tid + half_ * 1024;                                       \
            int i_ = b_ & 511;                                                 \
            unsigned* bb_ = B2 + (b_ >> 9) * 2048;                             \
            int j_ = (JEXPR);                                                  \
            int p0 = swz(j_), p1 = swz(j_ + (H)), p2 = swz(j_ + 2 * (H)),      \
                p3 = swz(j_ + 3 * (H));                                        \
            float s1, c1; __sincosf((ANGEXPR), &s1, &c1);                      \
            float c2 = c1 * c1 - s1 * s1, s2 = 2.f * c1 * s1;                  \
            float c3 = c1 * c2 - s1 * s2, s3 = s1 * c2 + c1 * s2;              \
            CORE(bb_, p0, p1, p2, p3, c1, s1, c2, s2, c3, s3);                 \
        }                                                                      \
    }                                                                          \
    __syncthreads();

// ---- fused: energy + in-reg radix-2 + 4x forward FFT (packed LDS) + tf max
__global__ __launch_bounds__(1024, 8) void k_fwd(const float* __restrict__ env,
                                                 const float* __restrict__ noise,
                                                 const float* __restrict__ tf,
                                                 float* __restrict__ ws) {
    __shared__ unsigned B2[8192];   // 4 FFTs x 2048 packed half2 = 32 KB
    int tid = threadIdx.x;
    int id = blockIdx.x;
    int xcd = id & 7, slot = id >> 3;
    int be = xcd * 16 + (slot >> 2);
    int fg = slot & 3;                       // f = fg*4 .. fg*4+3
    const float4* env4 = (const float4*)env;
    const float4* noi4 = (const float4*)noise;
    size_t base = (size_t)be * 16384 + fg;

    // thread t owns complexes t and t+1024: samples {2t,2t+1, 2t+2048,2t+2049}.
    // energy + radix-2 (h=1024) butterfly in registers, packed scatter.
    {
        float4 ea0 = env4[base + (size_t)(2 * tid) * 4];
        float4 ea1 = env4[base + (size_t)(2 * tid + 1) * 4];
        float4 eb0 = env4[base + (size_t)(2 * tid + 2048) * 4];
        float4 eb1 = env4[base + (size_t)(2 * tid + 2049) * 4];
        float4 za0 = noi4[base + (size_t)(2 * tid) * 4];
        float4 za1 = noi4[base + (size_t)(2 * tid + 1) * 4];
        float4 zb0 = noi4[base + (size_t)(2 * tid + 2048) * 4];
        float4 zb1 = noi4[base + (size_t)(2 * tid + 2049) * 4];
        float4 A0 = make_float4(ea0.x * (za0.x * 2.f - 1.f), ea0.y * (za0.y * 2.f - 1.f),
                                ea0.z * (za0.z * 2.f - 1.f), ea0.w * (za0.w * 2.f - 1.f));
        float4 A1 = make_float4(ea1.x * (za1.x * 2.f - 1.f), ea1.y * (za1.y * 2.f - 1.f),
                                ea1.z * (za1.z * 2.f - 1.f), ea1.w * (za1.w * 2.f - 1.f));
        float4 B0 = make_float4(eb0.x * (zb0.x * 2.f - 1.f), eb0.y * (zb0.y * 2.f - 1.f),
                                eb0.z * (zb0.z * 2.f - 1.f), eb0.w * (zb0.w * 2.f - 1.f));
        float4 B1 = make_float4(eb1.x * (zb1.x * 2.f - 1.f), eb1.y * (zb1.y * 2.f - 1.f),
                                eb1.z * (zb1.z * 2.f - 1.f), eb1.w * (zb1.w * 2.f - 1.f));
        const float* A0v = (const float*)&A0;
        const float* A1v = (const float*)&A1;
        const float* B0v = (const float*)&B0;
        const float* B1v = (const float*)&B1;
        float s, c; __sincosf((float)tid * (TWO_PI / 2048.0f), &s, &c);
        int pj = swz(tid), pjb = swz(tid + 1024);
#pragma unroll
        for (int j4 = 0; j4 < 4; ++j4) {
            float xr = A0v[j4], xi = A1v[j4];
            float yr = B0v[j4], yi = B1v[j4];
            unsigned* bb = B2 + j4 * 2048;
            float dr = xr - yr, di = xi - yi;
            bb[pj] = pkh(xr + yr, xi + yi);
            bb[pjb] = pkh(dr * c + di * s, di * c - dr * s);
        }
    }
    __syncthreads();
    STAGE4P(r4f_pk, (i_ >> 8) * 1024 + (i_ & 255), 256, (float)(i_ & 255) * (TWO_PI / 1024.0f));
    STAGE4P(r4f_pk, (i_ >> 6) * 256 + (i_ & 63), 64, (float)(i_ & 63) * (TWO_PI / 256.0f));
    STAGE4P(r4f_pk, (i_ & 31) * 64 + (i_ >> 5), 16, (float)(i_ >> 5) * (TWO_PI / 64.0f));
    STAGE4P(r4f_pk, (i_ & 127) * 16 + (i_ >> 7), 4, (float)(i_ >> 7) * (TWO_PI / 16.0f));
    STAGE4P(r4f_pk, i_ * 4, 1, 0.0f);
    // rfft unpack -> E (half2), indices/twiddles shared across the 4 buffers
    __half2* Ebase = (__half2*)(ws + OFF_E) + (size_t)(be * 16 + fg * 4) * 2049;
    for (int k = tid; k <= 1024; k += 1024) {
        int pk = swz(permf(k));
        int pm = swz(permf((2048 - k) & 2047));
        float s4, c4; __sincosf((float)k * (TWO_PI / 4096.0f), &s4, &c4);
#pragma unroll
        for (int j4 = 0; j4 < 4; ++j4) {
            unsigned* bb = B2 + j4 * 2048;
            float2 zk = uph(bb[pk]), zm = uph(bb[pm]);
            float xer = 0.5f * (zk.x + zm.x), xei = 0.5f * (zk.y - zm.y);
            float xor_ = 0.5f * (zk.y + zm.y), xoi = 0.5f * (zm.x - zk.x);
            float wr = xor_ * c4 + xoi * s4;
            float wi = xoi * c4 - xor_ * s4;
            __half2* Eg = Ebase + (size_t)j4 * 2049;
            Eg[k] = __floats2half2_rn(xer + wr, xei + wi);
            Eg[2048 - k] = __floats2half2_rn(xer - wr, wi - xei);
        }
    }
    __syncthreads();
    // tf max over this block's bin quarter (wave shuffle reduce, B2 as scratch)
    float* Bf = (float*)B2;
    const float4* ab4 = (const float4*)(tf + (size_t)be * 65568);
    int b0 = fg * 513;
    int nb = (fg == 3) ? 510 : 513;          // 3*513 + 510 = 2049 bins
    float mx = 0.f;
    for (int u = tid; u < nb * 4; u += 1024) {
        int g = u >> 2, e = u & 3;
        int bin = b0 + g;
        float4 A = ab4[bin * 8 + e];
        float4 Bv = ab4[bin * 8 + e + 4];
        mx = fmaxf(mx, fmaxf(fmaxf(A.x * A.x + Bv.x * Bv.x, A.y * A.y + Bv.y * Bv.y),
                             fmaxf(A.z * A.z + Bv.z * Bv.z, A.w * A.w + Bv.w * Bv.w)));
    }
#pragma unroll
    for (int off = 32; off > 0; off >>= 1)
        mx = fmaxf(mx, __shfl_xor(mx, off));
    if ((tid & 63) == 0) Bf[tid >> 6] = mx;
    __syncthreads();
    if (tid == 0) {
        float m = Bf[0];
#pragma unroll
        for (int i = 1; i < 16; ++i) m = fmaxf(m, Bf[i]);
        ws[OFF_MAXP + be * 4 + fg] = m;
    }
}

// ---- per-bin recurrence on pair (k, 2048-k) + fused irfft pre-pack -> Z' (half2)
__global__ __launch_bounds__(256) void k_recur(const float* __restrict__ tf,
                                               float* __restrict__ ws) {
    __shared__ float sm2lo[256 * 17], simlo[256 * 17];
    __shared__ float sm2hi[256 * 17], simhi[256 * 17];
    int tid = threadIdx.x;
    int be = blockIdx.y;
    int k0 = blockIdx.x << 8;          // 0,256,512,768
    int hi0 = 1793 - k0;               // hi bins [hi0, hi0+255]
    const float* tfb = tf + (size_t)be * 65568;
    const float4* ab4 = (const float4*)tfb;
    const float4* im4 = (const float4*)(tfb + 32784);

    for (int u = tid; u < 2048; u += 256) {
        int half = u >> 10, v = u & 1023;
        int g = v >> 2, e = v & 3;
        int bin = half ? (hi0 + g) : (k0 + g);
        float4 A = ab4[bin * 8 + e];
        float4 Bv = ab4[bin * 8 + e + 4];
        float4 I = im4[bin * 4 + e];
        int o = g * 17 + e * 4;
        float* sm = half ? sm2hi : sm2lo;
        float* si = half ? simhi : simlo;
        sm[o + 0] = A.x * A.x + Bv.x * Bv.x;
        sm[o + 1] = A.y * A.y + Bv.y * Bv.y;
        sm[o + 2] = A.z * A.z + Bv.z * Bv.z;
        sm[o + 3] = A.w * A.w + Bv.w * Bv.w;
        si[o + 0] = I.x; si[o + 1] = I.y; si[o + 2] = I.z; si[o + 3] = I.w;
    }
    __syncthreads();

    int k = k0 + tid;
    int m = 2048 - k;
    int rhi = 255 - tid;
    const float* mp = ws + OFF_MAXP + be * 4;
    float m2x = fmaxf(fmaxf(mp[0], mp[1]), fmaxf(mp[2], mp[3]));
    float rden = 1.0f / (sqrtf(m2x) + 1e-8f);
    const __half2* Eb = (const __half2*)(ws + OFF_E) + (size_t)be * 16 * 2049;
    __half2* Zb = (__half2*)(ws + OFF_Z) + (size_t)be * 16 * 2048;
    float2 evlo[16], evhi[16];
#pragma unroll
    for (int f = 0; f < 16; ++f) {
        evlo[f] = __half22float2(Eb[(size_t)f * 2049 + k]);
        evhi[f] = __half22float2(Eb[(size_t)f * 2049 + m]);
    }
    float ym = (k == 0) ? 0.0f : 1.0f;
    float s4, c4; __sincosf((float)k * (TWO_PI / 4096.0f), &s4, &c4);
    const float SCL = 1.0f / 2048.0f;
    float srl = 0.f, sil = 0.f, srh = 0.f, sih = 0.f;
#pragma unroll
    for (int f = 0; f < 16; ++f) {
        float mh = sqrtf(sm2lo[tid * 17 + f]) * rden;
        float ph = atan2f(simlo[tid * 17 + f], mh) * 3.14159265358979f;
        float sp, cp; __sincosf(ph, &sp, &cp);
        float Tr = mh * cp, Ti = mh * sp;
        sil *= ym;
        srl += evlo[f].x; sil += evlo[f].y;
        float nr = srl * Tr - sil * Ti;
        sil = srl * Ti + sil * Tr; srl = nr;
        float mh2 = sqrtf(sm2hi[rhi * 17 + f]) * rden;
        float ph2 = atan2f(simhi[rhi * 17 + f], mh2) * 3.14159265358979f;
        float sp2, cp2; __sincosf(ph2, &sp2, &cp2);
        float Tr2 = mh2 * cp2, Ti2 = mh2 * sp2;
        sih *= ym;
        srh += evhi[f].x; sih += evhi[f].y;
        float nr2 = srh * Tr2 - sih * Ti2;
        sih = srh * Ti2 + sih * Tr2; srh = nr2;
        __half2* Zf = Zb + (size_t)f * 2048;
        if (k == 0) {
            float y0 = srl * SCL, yn = srh * SCL;
            Zf[0] = __floats2half2_rn(0.5f * (y0 + yn), 0.5f * (y0 - yn));
        } else {
            float ykr = srl * SCL, yki = sil * SCL;
            float ymr = srh * SCL, ymi = sih * SCL;
            float er = 0.5f * (ykr + ymr), ei = 0.5f * (yki - ymi);
            float dr = ykr - ymr, di = yki + ymi;
            float orr = 0.5f * (dr * c4 - di * s4);
            float oi = 0.5f * (dr * s4 + di * c4);
            Zf[k] = __floats2half2_rn(er - oi, ei + orr);
            Zf[m] = __floats2half2_rn(er + oi, orr - ei);
        }
    }
    if (k0 == 0 && tid == 0) {   // bin 1024 (self-paired)
        float sr = 0.f, si = 0.f;
#pragma unroll
        for (int f = 0; f < 16; ++f) {
            float a = tfb[1024 * 32 + f];
            float b = tfb[1024 * 32 + 16 + f];
            float im = tfb[32784 + 1024 * 16 + f];
            float mh = sqrtf(a * a + b * b) * rden;
            float ph = atan2f(im, mh) * 3.14159265358979f;
            float sp, cp; __sincosf(ph, &sp, &cp);
            float Tr = mh * cp, Ti = mh * sp;
            float2 e = __half22float2(Eb[(size_t)f * 2049 + 1024]);
            sr += e.x; si += e.y;
            float nr = sr * Tr - si * Ti;
            si = sr * Ti + si * Tr; sr = nr;
            Zb[(size_t)f * 2048 + 1024] = __floats2half2_rn(sr * SCL, -si * SCL);
        }
    }
}

// ---- inverse FFT: 4 frames per block, packed half2 LDS, merged final radix-2
__global__ __launch_bounds__(1024, 8) void k_fft_inv(float* __restrict__ ws) {
    __shared__ unsigned B2[8192];   // 4 FFTs x 2048 packed half2 = 32 KB
    int tid = threadIdx.x;
    int be = blockIdx.x >> 2, fg = blockIdx.x & 3;
    const __half2* Zbase = (const __half2*)(ws + OFF_Z) + (size_t)(be * 16 + fg * 4) * 2048;
    {
        int n0 = tid * 2;
        int p0 = swz(permf(n0)), p1 = swz(permf(n0 + 1));
#pragma unroll
        for (int j4 = 0; j4 < 4; ++j4) {
            uint2 raw = ((const uint2*)(Zbase + (size_t)j4 * 2048))[tid];
            unsigned* bb = B2 + j4 * 2048;
            bb[p0] = raw.x;
            bb[p1] = raw.y;
        }
    }
    __syncthreads();
    STAGE4P(r4i_pk, i_ * 4, 1, 0.0f);
    STAGE4P(r4i_pk, (i_ & 127) * 16 + (i_ >> 7), 4, (float)(i_ >> 7) * (TWO_PI / 16.0f));
    STAGE4P(r4i_pk, (i_ & 31) * 64 + (i_ >> 5), 16, (float)(i_ >> 5) * (TWO_PI / 64.0f));
    STAGE4P(r4i_pk, (i_ >> 6) * 256 + (i_ & 63), 64, (float)(i_ & 63) * (TWO_PI / 256.0f));
    STAGE4P(r4i_pk, (i_ >> 8) * 1024 + (i_ & 255), 256, (float)(i_ & 255) * (TWO_PI / 1024.0f));
    // merged radix-2 (h=1024) + F writeback
    {
        int sj = swz(tid), sjb = swz(tid + 1024);
        float s, c; __sincosf((float)tid * (TWO_PI / 2048.0f), &s, &c);
        __half2* Fbase = (__half2*)(ws + OFF_F) + (size_t)(be * 16 + fg * 4) * 2048;
#pragma unroll
        for (int j4 = 0; j4 < 4; ++j4) {
            unsigned* bb = B2 + j4 * 2048;
            float2 a = uph(bb[sj]);
            float2 b = uph(bb[sjb]);
            float tr = b.x * c - b.y * s, ti2 = b.x * s + b.y * c;
            __half2* Fg = Fbase + (size_t)j4 * 2048;
            Fg[tid] = __floats2half2_rn(a.x + tr, a.y + ti2);
            Fg[tid + 1024] = __floats2half2_rn(a.x - tr, a.y - ti2);
        }
    }
}

// ---- gather + fused overlap-add (F half in, f32 out)
__global__ __launch_bounds__(256) void k_segment(const float* __restrict__ ws,
                                                 const int* __restrict__ indices,
                                                 float* __restrict__ out) {
    __shared__ int ste[16];
    int tid = threadIdx.x;
    int b = blockIdx.y;
    if (tid < 16) ste[tid] = indices[b * 16 + tid] * 256;
    __syncthreads();
    int g = blockIdx.x * 256 + tid;
    int t = g << 2;
    const __half* F = (const __half*)(ws + OFF_F);
    float4 acc = make_float4(0.f, 0.f, 0.f, 0.f);
#pragma unroll
    for (int e = 0; e < 16; ++e) {
        int te = ste[e];
        if (t >= te) {
            int d = t - te;
            int j = d >> 11, r = d & 2047;
            size_t base = (size_t)(b * 16 + e) * 65536;
            uint2 raw = *(const uint2*)(F + base + j * 4096 + r);
            float2 a0 = __half22float2(*(const __half2*)&raw.x);
            float2 a1 = __half22float2(*(const __half2*)&raw.y);
            acc.x += a0.x; acc.y += a0.y; acc.z += a1.x; acc.w += a1.y;
            if (j >= 1) {
                uint2 rw2 = *(const uint2*)(F + base + (j - 1) * 4096 + 2048 + r);
                float2 b0 = __half22float2(*(const __half2*)&rw2.x);
                float2 b1 = __half22float2(*(const __half2*)&rw2.y);
                acc.x += b0.x; acc.y += b0.y; acc.z += b1.x; acc.w += b1.y;
            }
        }
    }
    ((float4*)out)[(size_t)b * 8192 + g] = acc;
}

extern "C" void kernel_launch(void* const* d_in, const int* in_sizes, int n_in,
                              void* d_out, int out_size, void* d_ws, size_t ws_size,
                              hipStream_t stream) {
    const float* env = (const float*)d_in[0];
    const float* tf = (const float*)d_in[1];
    const float* noise = (const float*)d_in[2];
    const int* indices = (const int*)d_in[3];
    float* ws = (float*)d_ws;
    float* out = (float*)d_out;

    k_fwd<<<dim3(512), dim3(1024), 0, stream>>>(env, noise, tf, ws);
    k_recur<<<dim3(4, 128), dim3(256), 0, stream>>>(tf, ws);
    k_fft_inv<<<dim3(512), dim3(1024), 0, stream>>>(ws);
    k_segment<<<dim3(32, 8), dim3(256), 0, stream>>>(ws, indices, out);
}

// Round 15
// 75.243 us; speedup vs baseline: 1.0402x; 1.0313x over previous
//
#include <hip/hip_runtime.h>
#include <hip/hip_fp16.h>
#include <math.h>

#define TWO_PI 6.283185307179586f

// workspace layout (float offsets; E/Z/F regions hold halves)
#define OFF_F    0ull          // frames [be][f][4096] __half   = 4194304 floats
#define OFF_E    4194304ull    // E [be][f][2049] __half2       = 4196352 floats
#define OFF_MAXP 8390656ull    // 512 partial maxima (4 per be)
#define OFF_Z    8391680ull    // Z' [be][f][2048] __half2      = 4194304 floats

__device__ __forceinline__ int swz(int n) { return n ^ ((n >> 5) & 31); }

// position of natural index k after DIF with radices [2,4,4,4,4,4]
__device__ __forceinline__ int permf(int k) {
    return ((k & 1) << 10) | (((k >> 1) & 3) << 8) | (((k >> 3) & 3) << 6)
         | (((k >> 5) & 3) << 4) | (((k >> 7) & 3) << 2) | ((k >> 9) & 3);
}

__device__ __forceinline__ float2 uph(unsigned u) {
    __half2 h = *(__half2*)&u;
    return __half22float2(h);
}
__device__ __forceinline__ unsigned pkh(float x, float y) {
    __half2 h = __floats2half2_rn(x, y);
    return *(unsigned*)&h;
}

__device__ __forceinline__ void r4f_core(float* cr, float* ci, int p0, int p1, int p2, int p3,
                                         float c1, float s1, float c2, float s2, float c3, float s3) {
    float ar = cr[p0], ai = ci[p0];
    float br = cr[p1], bi = ci[p1];
    float crr = cr[p2], cri = ci[p2];
    float drr = cr[p3], dri = ci[p3];
    float u0r = ar + crr, u0i = ai + cri;
    float u1r = ar - crr, u1i = ai - cri;
    float u2r = br + drr, u2i = bi + dri;
    float u3r = br - drr, u3i = bi - dri;
    cr[p0] = u0r + u2r; ci[p0] = u0i + u2i;
    float z1r = u1r + u3i, z1i = u1i - u3r;            // u1 - i*u3
    cr[p1] = z1r * c1 + z1i * s1; ci[p1] = z1i * c1 - z1r * s1;
    float z2r = u0r - u2r, z2i = u0i - u2i;
    cr[p2] = z2r * c2 + z2i * s2; ci[p2] = z2i * c2 - z2r * s2;
    float z3r = u1r - u3i, z3i = u1i + u3r;            // u1 + i*u3
    cr[p3] = z3r * c3 + z3i * s3; ci[p3] = z3i * c3 - z3r * s3;
}

// packed half2 inverse radix-4 core
__device__ __forceinline__ void r4i_pk(unsigned* b, int p0, int p1, int p2, int p3,
                                       float c1, float s1, float c2, float s2, float c3, float s3) {
    float2 z0 = uph(b[p0]), z1 = uph(b[p1]), z2 = uph(b[p2]), z3 = uph(b[p3]);
    float t1r = z1.x * c1 - z1.y * s1, t1i = z1.y * c1 + z1.x * s1;
    float t2r = z2.x * c2 - z2.y * s2, t2i = z2.y * c2 + z2.x * s2;
    float t3r = z3.x * c3 - z3.y * s3, t3i = z3.y * c3 + z3.x * s3;
    float u0r = z0.x + t2r, u0i = z0.y + t2i;
    float u1r = z0.x - t2r, u1i = z0.y - t2i;
    float u2r = t1r + t3r, u2i = t1i + t3i;
    float u3r = t1r - t3r, u3i = t1i - t3i;
    b[p0] = pkh(u0r + u2r, u0i + u2i);
    b[p1] = pkh(u1r - u3i, u1i + u3r);                 // u1 + i*u3
    b[p2] = pkh(u0r - u2r, u0i - u2i);
    b[p3] = pkh(u1r + u3i, u1i - u3r);                 // u1 - i*u3
}

// forward: one radix-4 stage over 4 f32 buffers with 1024 threads
#define STAGE4X(CORE, JEXPR, H, ANGEXPR)                                       \
    {                                                                          \
        _Pragma("unroll")                                                      \
        for (int half_ = 0; half_ < 2; ++half_) {                              \
            int b_ = tid + half_ * 1024;                                       \
            int i_ = b_ & 511;                                                 \
            float* cr_ = B + (b_ >> 9) * 4096;                                 \
            float* ci_ = cr_ + 2048;                                           \
            int j_ = (JEXPR);                                                  \
            int p0 = swz(j_), p1 = swz(j_ + (H)), p2 = swz(j_ + 2 * (H)),      \
                p3 = swz(j_ + 3 * (H));                                        \
            float s1, c1; __sincosf((ANGEXPR), &s1, &c1);                      \
            float c2 = c1 * c1 - s1 * s1, s2 = 2.f * c1 * s1;                  \
            float c3 = c1 * c2 - s1 * s2, s3 = s1 * c2 + c1 * s2;              \
            CORE(cr_, ci_, p0, p1, p2, p3, c1, s1, c2, s2, c3, s3);            \
        }                                                                      \
    }                                                                          \
    __syncthreads();

// inverse: one radix-4 stage over 4 packed buffers with 1024 threads
#define STAGE4P(JEXPR, H, ANGEXPR)                                             \
    {                                                                          \
        _Pragma("unroll")                                                      \
        for (int half_ = 0; half_ < 2; ++half_) {                              \
            int b_ = tid + half_ * 1024;                                       \
            int i_ = b_ & 511;                                                 \
            unsigned* bb_ = B2 + (b_ >> 9) * 2048;                             \
            int j_ = (JEXPR);                                                  \
            int p0 = swz(j_), p1 = swz(j_ + (H)), p2 = swz(j_ + 2 * (H)),      \
                p3 = swz(j_ + 3 * (H));                                        \
            float s1, c1; __sincosf((ANGEXPR), &s1, &c1);                      \
            float c2 = c1 * c1 - s1 * s1, s2 = 2.f * c1 * s1;                  \
            float c3 = c1 * c2 - s1 * s2, s3 = s1 * c2 + c1 * s2;              \
            r4i_pk(bb_, p0, p1, p2, p3, c1, s1, c2, s2, c3, s3);               \
        }                                                                      \
    }                                                                          \
    __syncthreads();

// ---- fused: energy + 4x forward FFT + per-quarter tf max (512 blocks, 2/CU)
//      (round-11 form: fastest measured at 40.2 us)
__global__ __launch_bounds__(1024, 8) void k_fwd(const float* __restrict__ env,
                                                 const float* __restrict__ noise,
                                                 const float* __restrict__ tf,
                                                 float* __restrict__ ws) {
    __shared__ float B[16384];   // 4 FFTs x (cr[2048], ci[2048]) = 64 KB
    int tid = threadIdx.x;
    int id = blockIdx.x;
    int xcd = id & 7, slot = id >> 3;
    int be = xcd * 16 + (slot >> 2);
    int fg = slot & 3;                       // f = fg*4 .. fg*4+3
    const float4* env4 = (const float4*)env;
    const float4* noi4 = (const float4*)noise;
    size_t base = (size_t)be * 16384 + fg;
#pragma unroll
    for (int it = 0; it < 4; ++it) {
        int n = it * 1024 + tid;
        float4 e = env4[base + (size_t)n * 4];
        float4 z = noi4[base + (size_t)n * 4];
        float v0 = e.x * (z.x * 2.0f - 1.0f);
        float v1 = e.y * (z.y * 2.0f - 1.0f);
        float v2 = e.z * (z.z * 2.0f - 1.0f);
        float v3 = e.w * (z.w * 2.0f - 1.0f);
        int m = swz(n >> 1) + (n & 1) * 2048;   // cr at +0, ci at +2048
        B[m] = v0; B[4096 + m] = v1; B[8192 + m] = v2; B[12288 + m] = v3;
    }
    __syncthreads();
    // radix-2 DIF, h=1024 (twiddle shared across buffers)
    {
        int i = tid;
        int sj = swz(i), sjb = swz(i + 1024);
        float s, c; __sincosf((float)i * (TWO_PI / 2048.0f), &s, &c);
#pragma unroll
        for (int j4 = 0; j4 < 4; ++j4) {
            float* cr = B + j4 * 4096;
            float* ci = cr + 2048;
            float ar = cr[sj], ai = ci[sj], br = cr[sjb], bi = ci[sjb];
            float dr = ar - br, di = ai - bi;
            cr[sj] = ar + br; ci[sj] = ai + bi;
            cr[sjb] = dr * c + di * s; ci[sjb] = di * c - dr * s;
        }
    }
    __syncthreads();
    STAGE4X(r4f_core, (i_ >> 8) * 1024 + (i_ & 255), 256, (float)(i_ & 255) * (TWO_PI / 1024.0f));
    STAGE4X(r4f_core, (i_ >> 6) * 256 + (i_ & 63), 64, (float)(i_ & 63) * (TWO_PI / 256.0f));
    STAGE4X(r4f_core, (i_ & 31) * 64 + (i_ >> 5), 16, (float)(i_ >> 5) * (TWO_PI / 64.0f));
    STAGE4X(r4f_core, (i_ & 127) * 16 + (i_ >> 7), 4, (float)(i_ >> 7) * (TWO_PI / 16.0f));
    STAGE4X(r4f_core, i_ * 4, 1, 0.0f);
    // rfft unpack -> E (half2), indices/twiddles shared across the 4 buffers
    __half2* Ebase = (__half2*)(ws + OFF_E) + (size_t)(be * 16 + fg * 4) * 2049;
    for (int k = tid; k <= 1024; k += 1024) {
        int pk = swz(permf(k));
        int pm = swz(permf((2048 - k) & 2047));
        float s4, c4; __sincosf((float)k * (TWO_PI / 4096.0f), &s4, &c4);
#pragma unroll
        for (int j4 = 0; j4 < 4; ++j4) {
            float* cr = B + j4 * 4096;
            float* ci = cr + 2048;
            float zkr = cr[pk], zki = ci[pk], zmr = cr[pm], zmi = ci[pm];
            float xer = 0.5f * (zkr + zmr), xei = 0.5f * (zki - zmi);
            float xor_ = 0.5f * (zki + zmi), xoi = 0.5f * (zmr - zkr);
            float wr = xor_ * c4 + xoi * s4;
            float wi = xoi * c4 - xor_ * s4;
            __half2* Eg = Ebase + (size_t)j4 * 2049;
            Eg[k] = __floats2half2_rn(xer + wr, xei + wi);
            Eg[2048 - k] = __floats2half2_rn(xer - wr, wi - xei);
        }
    }
    __syncthreads();
    // tf max over this block's bin quarter (reuses B)
    const float4* ab4 = (const float4*)(tf + (size_t)be * 65568);
    int b0 = fg * 513;
    int nb = (fg == 3) ? 510 : 513;          // 3*513 + 510 = 2049 bins
    float mx = 0.f;
    for (int u = tid; u < nb * 4; u += 1024) {
        int g = u >> 2, e = u & 3;
        int bin = b0 + g;
        float4 A = ab4[bin * 8 + e];
        float4 Bv = ab4[bin * 8 + e + 4];
        mx = fmaxf(mx, fmaxf(fmaxf(A.x * A.x + Bv.x * Bv.x, A.y * A.y + Bv.y * Bv.y),
                             fmaxf(A.z * A.z + Bv.z * Bv.z, A.w * A.w + Bv.w * Bv.w)));
    }
    B[tid] = mx;
    __syncthreads();
    for (int s = 512; s > 0; s >>= 1) {
        if (tid < s) B[tid] = fmaxf(B[tid], B[tid + s]);
        __syncthreads();
    }
    if (tid == 0) ws[OFF_MAXP + be * 4 + fg] = B[0];
}

// ---- per-bin recurrence on pair (k, 2048-k) + fused irfft pre-pack -> Z' (half2)
__global__ __launch_bounds__(256) void k_recur(const float* __restrict__ tf,
                                               float* __restrict__ ws) {
    __shared__ float sm2lo[256 * 17], simlo[256 * 17];
    __shared__ float sm2hi[256 * 17], simhi[256 * 17];
    int tid = threadIdx.x;
    int be = blockIdx.y;
    int k0 = blockIdx.x << 8;          // 0,256,512,768
    int hi0 = 1793 - k0;               // hi bins [hi0, hi0+255]
    const float* tfb = tf + (size_t)be * 65568;
    const float4* ab4 = (const float4*)tfb;
    const float4* im4 = (const float4*)(tfb + 32784);

    for (int u = tid; u < 2048; u += 256) {
        int half = u >> 10, v = u & 1023;
        int g = v >> 2, e = v & 3;
        int bin = half ? (hi0 + g) : (k0 + g);
        float4 A = ab4[bin * 8 + e];
        float4 Bv = ab4[bin * 8 + e + 4];
        float4 I = im4[bin * 4 + e];
        int o = g * 17 + e * 4;
        float* sm = half ? sm2hi : sm2lo;
        float* si = half ? simhi : simlo;
        sm[o + 0] = A.x * A.x + Bv.x * Bv.x;
        sm[o + 1] = A.y * A.y + Bv.y * Bv.y;
        sm[o + 2] = A.z * A.z + Bv.z * Bv.z;
        sm[o + 3] = A.w * A.w + Bv.w * Bv.w;
        si[o + 0] = I.x; si[o + 1] = I.y; si[o + 2] = I.z; si[o + 3] = I.w;
    }
    __syncthreads();

    int k = k0 + tid;
    int m = 2048 - k;
    int rhi = 255 - tid;
    const float* mp = ws + OFF_MAXP + be * 4;
    float m2x = fmaxf(fmaxf(mp[0], mp[1]), fmaxf(mp[2], mp[3]));
    float rden = 1.0f / (sqrtf(m2x) + 1e-8f);
    const __half2* Eb = (const __half2*)(ws + OFF_E) + (size_t)be * 16 * 2049;
    __half2* Zb = (__half2*)(ws + OFF_Z) + (size_t)be * 16 * 2048;
    float2 evlo[16], evhi[16];
#pragma unroll
    for (int f = 0; f < 16; ++f) {
        evlo[f] = __half22float2(Eb[(size_t)f * 2049 + k]);
        evhi[f] = __half22float2(Eb[(size_t)f * 2049 + m]);
    }
    float ym = (k == 0) ? 0.0f : 1.0f;
    float s4, c4; __sincosf((float)k * (TWO_PI / 4096.0f), &s4, &c4);
    const float SCL = 1.0f / 2048.0f;
    float srl = 0.f, sil = 0.f, srh = 0.f, sih = 0.f;
#pragma unroll
    for (int f = 0; f < 16; ++f) {
        float mh = sqrtf(sm2lo[tid * 17 + f]) * rden;
        float ph = atan2f(simlo[tid * 17 + f], mh) * 3.14159265358979f;
        float sp, cp; __sincosf(ph, &sp, &cp);
        float Tr = mh * cp, Ti = mh * sp;
        sil *= ym;
        srl += evlo[f].x; sil += evlo[f].y;
        float nr = srl * Tr - sil * Ti;
        sil = srl * Ti + sil * Tr; srl = nr;
        float mh2 = sqrtf(sm2hi[rhi * 17 + f]) * rden;
        float ph2 = atan2f(simhi[rhi * 17 + f], mh2) * 3.14159265358979f;
        float sp2, cp2; __sincosf(ph2, &sp2, &cp2);
        float Tr2 = mh2 * cp2, Ti2 = mh2 * sp2;
        sih *= ym;
        srh += evhi[f].x; sih += evhi[f].y;
        float nr2 = srh * Tr2 - sih * Ti2;
        sih = srh * Ti2 + sih * Tr2; srh = nr2;
        __half2* Zf = Zb + (size_t)f * 2048;
        if (k == 0) {
            float y0 = srl * SCL, yn = srh * SCL;
            Zf[0] = __floats2half2_rn(0.5f * (y0 + yn), 0.5f * (y0 - yn));
        } else {
            float ykr = srl * SCL, yki = sil * SCL;
            float ymr = srh * SCL, ymi = sih * SCL;
            float er = 0.5f * (ykr + ymr), ei = 0.5f * (yki - ymi);
            float dr = ykr - ymr, di = yki + ymi;
            float orr = 0.5f * (dr * c4 - di * s4);
            float oi = 0.5f * (dr * s4 + di * c4);
            Zf[k] = __floats2half2_rn(er - oi, ei + orr);
            Zf[m] = __floats2half2_rn(er + oi, orr - ei);
        }
    }
    if (k0 == 0 && tid == 0) {   // bin 1024 (self-paired)
        float sr = 0.f, si = 0.f;
#pragma unroll
        for (int f = 0; f < 16; ++f) {
            float a = tfb[1024 * 32 + f];
            float b = tfb[1024 * 32 + 16 + f];
            float im = tfb[32784 + 1024 * 16 + f];
            float mh = sqrtf(a * a + b * b) * rden;
            float ph = atan2f(im, mh) * 3.14159265358979f;
            float sp, cp; __sincosf(ph, &sp, &cp);
            float Tr = mh * cp, Ti = mh * sp;
            float2 e = __half22float2(Eb[(size_t)f * 2049 + 1024]);
            sr += e.x; si += e.y;
            float nr = sr * Tr - si * Ti;
            si = sr * Ti + si * Tr; sr = nr;
            Zb[(size_t)f * 2048 + 1024] = __floats2half2_rn(sr * SCL, -si * SCL);
        }
    }
}

// ---- inverse FFT: 4 frames per block, packed half2 LDS, merged final radix-2
__global__ __launch_bounds__(1024, 8) void k_fft_inv(float* __restrict__ ws) {
    __shared__ unsigned B2[8192];   // 4 FFTs x 2048 packed half2 = 32 KB
    int tid = threadIdx.x;
    int be = blockIdx.x >> 2, fg = blockIdx.x & 3;
    const __half2* Zbase = (const __half2*)(ws + OFF_Z) + (size_t)(be * 16 + fg * 4) * 2048;
    {
        int n0 = tid * 2;
        int p0 = swz(permf(n0)), p1 = swz(permf(n0 + 1));
#pragma unroll
        for (int j4 = 0; j4 < 4; ++j4) {
            uint2 raw = ((const uint2*)(Zbase + (size_t)j4 * 2048))[tid];
            unsigned* bb = B2 + j4 * 2048;
            bb[p0] = raw.x;
            bb[p1] = raw.y;
        }
    }
    __syncthreads();
    STAGE4P(i_ * 4, 1, 0.0f);
    STAGE4P((i_ & 127) * 16 + (i_ >> 7), 4, (float)(i_ >> 7) * (TWO_PI / 16.0f));
    STAGE4P((i_ & 31) * 64 + (i_ >> 5), 16, (float)(i_ >> 5) * (TWO_PI / 64.0f));
    STAGE4P((i_ >> 6) * 256 + (i_ & 63), 64, (float)(i_ & 63) * (TWO_PI / 256.0f));
    STAGE4P((i_ >> 8) * 1024 + (i_ & 255), 256, (float)(i_ & 255) * (TWO_PI / 1024.0f));
    // merged radix-2 (h=1024) + F writeback
    {
        int sj = swz(tid), sjb = swz(tid + 1024);
        float s, c; __sincosf((float)tid * (TWO_PI / 2048.0f), &s, &c);
        __half2* Fbase = (__half2*)(ws + OFF_F) + (size_t)(be * 16 + fg * 4) * 2048;
#pragma unroll
        for (int j4 = 0; j4 < 4; ++j4) {
            unsigned* bb = B2 + j4 * 2048;
            float2 a = uph(bb[sj]);
            float2 b = uph(bb[sjb]);
            float tr = b.x * c - b.y * s, ti2 = b.x * s + b.y * c;
            __half2* Fg = Fbase + (size_t)j4 * 2048;
            Fg[tid] = __floats2half2_rn(a.x + tr, a.y + ti2);
            Fg[tid + 1024] = __floats2half2_rn(a.x - tr, a.y - ti2);
        }
    }
}

// ---- gather + fused overlap-add (F half in, f32 out)
__global__ __launch_bounds__(256) void k_segment(const float* __restrict__ ws,
                                                 const int* __restrict__ indices,
                                                 float* __restrict__ out) {
    __shared__ int ste[16];
    int tid = threadIdx.x;
    int b = blockIdx.y;
    if (tid < 16) ste[tid] = indices[b * 16 + tid] * 256;
    __syncthreads();
    int g = blockIdx.x * 256 + tid;
    int t = g << 2;
    const __half* F = (const __half*)(ws + OFF_F);
    float4 acc = make_float4(0.f, 0.f, 0.f, 0.f);
#pragma unroll
    for (int e = 0; e < 16; ++e) {
        int te = ste[e];
        if (t >= te) {
            int d = t - te;
            int j = d >> 11, r = d & 2047;
            size_t base = (size_t)(b * 16 + e) * 65536;
            uint2 raw = *(const uint2*)(F + base + j * 4096 + r);
            float2 a0 = __half22float2(*(const __half2*)&raw.x);
            float2 a1 = __half22float2(*(const __half2*)&raw.y);
            acc.x += a0.x; acc.y += a0.y; acc.z += a1.x; acc.w += a1.y;
            if (j >= 1) {
                uint2 rw2 = *(const uint2*)(F + base + (j - 1) * 4096 + 2048 + r);
                float2 b0 = __half22float2(*(const __half2*)&rw2.x);
                float2 b1 = __half22float2(*(const __half2*)&rw2.y);
                acc.x += b0.x; acc.y += b0.y; acc.z += b1.x; acc.w += b1.y;
            }
        }
    }
    ((float4*)out)[(size_t)b * 8192 + g] = acc;
}

extern "C" void kernel_launch(void* const* d_in, const int* in_sizes, int n_in,
                              void* d_out, int out_size, void* d_ws, size_t ws_size,
                              hipStream_t stream) {
    const float* env = (const float*)d_in[0];
    const float* tf = (const float*)d_in[1];
    const float* noise = (const float*)d_in[2];
    const int* indices = (const int*)d_in[3];
    float* ws = (float*)d_ws;
    float* out = (float*)d_out;

    k_fwd<<<dim3(512), dim3(1024), 0, stream>>>(env, noise, tf, ws);
    k_recur<<<dim3(4, 128), dim3(256), 0, stream>>>(tf, ws);
    k_fft_inv<<<dim3(512), dim3(1024), 0, stream>>>(ws);
    k_segment<<<dim3(32, 8), dim3(256), 0, stream>>>(ws, indices, out);
}

// Round 16
// 74.017 us; speedup vs baseline: 1.0574x; 1.0166x over previous
//
#include <hip/hip_runtime.h>
#include <hip/hip_fp16.h>
#include <math.h>

#define TWO_PI 6.283185307179586f

// workspace layout (float offsets; E/Z/F regions hold halves)
#define OFF_F    0ull          // frames [be][f][4096] __half   = 4194304 floats
#define OFF_E    4194304ull    // E [be][f][2049] __half2       = 4196352 floats
#define OFF_MAXP 8390656ull    // 512 partial maxima (4 per be)
#define OFF_Z    8391680ull    // Z' [be][f][2048] __half2      = 4194304 floats

__device__ __forceinline__ int swz(int n) { return n ^ ((n >> 5) & 31); }

// position of natural index k after DIF with radices [2,4,4,4,4,4] (inverse kernel)
__device__ __forceinline__ int permf(int k) {
    return ((k & 1) << 10) | (((k >> 1) & 3) << 8) | (((k >> 3) & 3) << 6)
         | (((k >> 5) & 3) << 4) | (((k >> 7) & 3) << 2) | ((k >> 9) & 3);
}
// position of natural index k after DIF with radices [8,4,4,4,4] (forward kernel)
__device__ __forceinline__ int perm8(int k) {
    return ((k & 7) << 8) | (((k >> 3) & 3) << 6) | (((k >> 5) & 3) << 4)
         | (((k >> 7) & 3) << 2) | ((k >> 9) & 3);
}

__device__ __forceinline__ float2 uph(unsigned u) {
    __half2 h = *(__half2*)&u;
    return __half22float2(h);
}
__device__ __forceinline__ unsigned pkh(float x, float y) {
    __half2 h = __floats2half2_rn(x, y);
    return *(unsigned*)&h;
}

__device__ __forceinline__ void r4f_core(float* cr, float* ci, int p0, int p1, int p2, int p3,
                                         float c1, float s1, float c2, float s2, float c3, float s3) {
    float ar = cr[p0], ai = ci[p0];
    float br = cr[p1], bi = ci[p1];
    float crr = cr[p2], cri = ci[p2];
    float drr = cr[p3], dri = ci[p3];
    float u0r = ar + crr, u0i = ai + cri;
    float u1r = ar - crr, u1i = ai - cri;
    float u2r = br + drr, u2i = bi + dri;
    float u3r = br - drr, u3i = bi - dri;
    cr[p0] = u0r + u2r; ci[p0] = u0i + u2i;
    float z1r = u1r + u3i, z1i = u1i - u3r;            // u1 - i*u3
    cr[p1] = z1r * c1 + z1i * s1; ci[p1] = z1i * c1 - z1r * s1;
    float z2r = u0r - u2r, z2i = u0i - u2i;
    cr[p2] = z2r * c2 + z2i * s2; ci[p2] = z2i * c2 - z2r * s2;
    float z3r = u1r - u3i, z3i = u1i + u3r;            // u1 + i*u3
    cr[p3] = z3r * c3 + z3i * s3; ci[p3] = z3i * c3 - z3r * s3;
}

// packed half2 inverse radix-4 core
__device__ __forceinline__ void r4i_pk(unsigned* b, int p0, int p1, int p2, int p3,
                                       float c1, float s1, float c2, float s2, float c3, float s3) {
    float2 z0 = uph(b[p0]), z1 = uph(b[p1]), z2 = uph(b[p2]), z3 = uph(b[p3]);
    float t1r = z1.x * c1 - z1.y * s1, t1i = z1.y * c1 + z1.x * s1;
    float t2r = z2.x * c2 - z2.y * s2, t2i = z2.y * c2 + z2.x * s2;
    float t3r = z3.x * c3 - z3.y * s3, t3i = z3.y * c3 + z3.x * s3;
    float u0r = z0.x + t2r, u0i = z0.y + t2i;
    float u1r = z0.x - t2r, u1i = z0.y - t2i;
    float u2r = t1r + t3r, u2i = t1i + t3i;
    float u3r = t1r - t3r, u3i = t1i - t3i;
    b[p0] = pkh(u0r + u2r, u0i + u2i);
    b[p1] = pkh(u1r - u3i, u1i + u3r);                 // u1 + i*u3
    b[p2] = pkh(u0r - u2r, u0i - u2i);
    b[p3] = pkh(u1r + u3i, u1i - u3r);                 // u1 - i*u3
}

// forward: one radix-4 stage over 4 f32 buffers with 1024 threads
#define STAGE4X(CORE, JEXPR, H, ANGEXPR)                                       \
    {                                                                          \
        _Pragma("unroll")                                                      \
        for (int half_ = 0; half_ < 2; ++half_) {                              \
            int b_ = tid + half_ * 1024;                                       \
            int i_ = b_ & 511;                                                 \
            float* cr_ = B + (b_ >> 9) * 4096;                                 \
            float* ci_ = cr_ + 2048;                                           \
            int j_ = (JEXPR);                                                  \
            int p0 = swz(j_), p1 = swz(j_ + (H)), p2 = swz(j_ + 2 * (H)),      \
                p3 = swz(j_ + 3 * (H));                                        \
            float s1, c1; __sincosf((ANGEXPR), &s1, &c1);                      \
            float c2 = c1 * c1 - s1 * s1, s2 = 2.f * c1 * s1;                  \
            float c3 = c1 * c2 - s1 * s2, s3 = s1 * c2 + c1 * s2;              \
            CORE(cr_, ci_, p0, p1, p2, p3, c1, s1, c2, s2, c3, s3);            \
        }                                                                      \
    }                                                                          \
    __syncthreads();

// inverse: one radix-4 stage over 4 packed buffers with 1024 threads
#define STAGE4P(JEXPR, H, ANGEXPR)                                             \
    {                                                                          \
        _Pragma("unroll")                                                      \
        for (int half_ = 0; half_ < 2; ++half_) {                              \
            int b_ = tid + half_ * 1024;                                       \
            int i_ = b_ & 511;                                                 \
            unsigned* bb_ = B2 + (b_ >> 9) * 2048;                             \
            int j_ = (JEXPR);                                                  \
            int p0 = swz(j_), p1 = swz(j_ + (H)), p2 = swz(j_ + 2 * (H)),      \
                p3 = swz(j_ + 3 * (H));                                        \
            float s1, c1; __sincosf((ANGEXPR), &s1, &c1);                      \
            float c2 = c1 * c1 - s1 * s1, s2 = 2.f * c1 * s1;                  \
            float c3 = c1 * c2 - s1 * s2, s3 = s1 * c2 + c1 * s2;              \
            r4i_pk(bb_, p0, p1, p2, p3, c1, s1, c2, s2, c3, s3);               \
        }                                                                      \
    }                                                                          \
    __syncthreads();

// ---- fused: energy + 4x forward FFT (radices [8,4,4,4,4]) + per-quarter tf max
__global__ __launch_bounds__(1024, 8) void k_fwd(const float* __restrict__ env,
                                                 const float* __restrict__ noise,
                                                 const float* __restrict__ tf,
                                                 float* __restrict__ ws) {
    __shared__ float B[16384];   // 4 FFTs x (cr[2048], ci[2048]) = 64 KB
    int tid = threadIdx.x;
    int id = blockIdx.x;
    int xcd = id & 7, slot = id >> 3;
    int be = xcd * 16 + (slot >> 2);
    int fg = slot & 3;                       // f = fg*4 .. fg*4+3
    const float4* env4 = (const float4*)env;
    const float4* noi4 = (const float4*)noise;
    size_t base = (size_t)be * 16384 + fg;
#pragma unroll
    for (int it = 0; it < 4; ++it) {
        int n = it * 1024 + tid;
        float4 e = env4[base + (size_t)n * 4];
        float4 z = noi4[base + (size_t)n * 4];
        float v0 = e.x * (z.x * 2.0f - 1.0f);
        float v1 = e.y * (z.y * 2.0f - 1.0f);
        float v2 = e.z * (z.z * 2.0f - 1.0f);
        float v3 = e.w * (z.w * 2.0f - 1.0f);
        int m = swz(n >> 1) + (n & 1) * 2048;   // cr at +0, ci at +2048
        B[m] = v0; B[4096 + m] = v1; B[8192 + m] = v2; B[12288 + m] = v3;
    }
    __syncthreads();
    // radix-8 DIF at stride 256 (replaces r2@1024 + r4@256): 1 butterfly/thread
    {
        int buf = tid >> 8, j = tid & 255;
        float* cr = B + buf * 4096;
        float* ci = cr + 2048;
        int p[8];
#pragma unroll
        for (int m = 0; m < 8; ++m) p[m] = swz(j + 256 * m);
        float xr[8], xi[8];
#pragma unroll
        for (int m = 0; m < 8; ++m) { xr[m] = cr[p[m]]; xi[m] = ci[p[m]]; }
        float t0r = xr[0] + xr[4], t0i = xi[0] + xi[4];
        float t1r = xr[0] - xr[4], t1i = xi[0] - xi[4];
        float t2r = xr[2] + xr[6], t2i = xi[2] + xi[6];
        float t3r = xr[2] - xr[6], t3i = xi[2] - xi[6];
        float A0r = t0r + t2r, A0i = t0i + t2i;
        float A2r = t0r - t2r, A2i = t0i - t2i;
        float A1r = t1r + t3i, A1i = t1i - t3r;   // t1 - i t3
        float A3r = t1r - t3i, A3i = t1i + t3r;   // t1 + i t3
        float u0r = xr[1] + xr[5], u0i = xi[1] + xi[5];
        float u1r = xr[1] - xr[5], u1i = xi[1] - xi[5];
        float u2r = xr[3] + xr[7], u2i = xi[3] + xi[7];
        float u3r = xr[3] - xr[7], u3i = xi[3] - xi[7];
        float B0r = u0r + u2r, B0i = u0i + u2i;
        float B2r = u0r - u2r, B2i = u0i - u2i;
        float B1r = u1r + u3i, B1i = u1i - u3r;
        float B3r = u1r - u3i, B3i = u1i + u3r;
        const float RH = 0.70710678118654752f;
        float b1r = (B1r + B1i) * RH, b1i = (B1i - B1r) * RH;   // W8^1 B1
        float b2r = B2i, b2i = -B2r;                            // -i B2
        float b3r = (B3i - B3r) * RH, b3i = -(B3r + B3i) * RH;  // W8^3 B3
        float yr[8], yi[8];
        yr[0] = A0r + B0r; yi[0] = A0i + B0i; yr[4] = A0r - B0r; yi[4] = A0i - B0i;
        yr[1] = A1r + b1r; yi[1] = A1i + b1i; yr[5] = A1r - b1r; yi[5] = A1i - b1i;
        yr[2] = A2r + b2r; yi[2] = A2i + b2i; yr[6] = A2r - b2r; yi[6] = A2i - b2i;
        yr[3] = A3r + b3r; yi[3] = A3i + b3i; yr[7] = A3r - b3r; yi[7] = A3i - b3i;
        float s1, c1; __sincosf((float)j * (TWO_PI / 2048.0f), &s1, &c1);
        float wr = c1, wi = -s1;     // W^j
        float cwr = wr, cwi = wi;
        cr[p[0]] = yr[0]; ci[p[0]] = yi[0];
#pragma unroll
        for (int m = 1; m < 8; ++m) {
            cr[p[m]] = yr[m] * cwr - yi[m] * cwi;
            ci[p[m]] = yr[m] * cwi + yi[m] * cwr;
            if (m < 7) {
                float nr = cwr * wr - cwi * wi;
                cwi = cwr * wi + cwi * wr;
                cwr = nr;
            }
        }
    }
    __syncthreads();
    STAGE4X(r4f_core, (i_ >> 6) * 256 + (i_ & 63), 64, (float)(i_ & 63) * (TWO_PI / 256.0f));
    STAGE4X(r4f_core, (i_ & 31) * 64 + (i_ >> 5), 16, (float)(i_ >> 5) * (TWO_PI / 64.0f));
    STAGE4X(r4f_core, (i_ & 127) * 16 + (i_ >> 7), 4, (float)(i_ >> 7) * (TWO_PI / 16.0f));
    STAGE4X(r4f_core, i_ * 4, 1, 0.0f);
    // rfft unpack -> E (half2), indices/twiddles shared across the 4 buffers
    __half2* Ebase = (__half2*)(ws + OFF_E) + (size_t)(be * 16 + fg * 4) * 2049;
    for (int k = tid; k <= 1024; k += 1024) {
        int pk = swz(perm8(k));
        int pm = swz(perm8((2048 - k) & 2047));
        float s4, c4; __sincosf((float)k * (TWO_PI / 4096.0f), &s4, &c4);
#pragma unroll
        for (int j4 = 0; j4 < 4; ++j4) {
            float* cr = B + j4 * 4096;
            float* ci = cr + 2048;
            float zkr = cr[pk], zki = ci[pk], zmr = cr[pm], zmi = ci[pm];
            float xer = 0.5f * (zkr + zmr), xei = 0.5f * (zki - zmi);
            float xor_ = 0.5f * (zki + zmi), xoi = 0.5f * (zmr - zkr);
            float wr = xor_ * c4 + xoi * s4;
            float wi = xoi * c4 - xor_ * s4;
            __half2* Eg = Ebase + (size_t)j4 * 2049;
            Eg[k] = __floats2half2_rn(xer + wr, xei + wi);
            Eg[2048 - k] = __floats2half2_rn(xer - wr, wi - xei);
        }
    }
    __syncthreads();
    // tf max over this block's bin quarter (wave shuffle reduce, B as scratch)
    const float4* ab4 = (const float4*)(tf + (size_t)be * 65568);
    int b0 = fg * 513;
    int nb = (fg == 3) ? 510 : 513;          // 3*513 + 510 = 2049 bins
    float mx = 0.f;
    for (int u = tid; u < nb * 4; u += 1024) {
        int g = u >> 2, e = u & 3;
        int bin = b0 + g;
        float4 A = ab4[bin * 8 + e];
        float4 Bv = ab4[bin * 8 + e + 4];
        mx = fmaxf(mx, fmaxf(fmaxf(A.x * A.x + Bv.x * Bv.x, A.y * A.y + Bv.y * Bv.y),
                             fmaxf(A.z * A.z + Bv.z * Bv.z, A.w * A.w + Bv.w * Bv.w)));
    }
#pragma unroll
    for (int off = 32; off > 0; off >>= 1)
        mx = fmaxf(mx, __shfl_xor(mx, off));
    if ((tid & 63) == 0) B[tid >> 6] = mx;
    __syncthreads();
    if (tid == 0) {
        float m = B[0];
#pragma unroll
        for (int i = 1; i < 16; ++i) m = fmaxf(m, B[i]);
        ws[OFF_MAXP + be * 4 + fg] = m;
    }
}

// ---- per-bin recurrence on pair (k, 2048-k) + fused irfft pre-pack -> Z' (half2)
__global__ __launch_bounds__(256) void k_recur(const float* __restrict__ tf,
                                               float* __restrict__ ws) {
    __shared__ float sm2lo[256 * 17], simlo[256 * 17];
    __shared__ float sm2hi[256 * 17], simhi[256 * 17];
    int tid = threadIdx.x;
    int be = blockIdx.y;
    int k0 = blockIdx.x << 8;          // 0,256,512,768
    int hi0 = 1793 - k0;               // hi bins [hi0, hi0+255]
    const float* tfb = tf + (size_t)be * 65568;
    const float4* ab4 = (const float4*)tfb;
    const float4* im4 = (const float4*)(tfb + 32784);

    for (int u = tid; u < 2048; u += 256) {
        int half = u >> 10, v = u & 1023;
        int g = v >> 2, e = v & 3;
        int bin = half ? (hi0 + g) : (k0 + g);
        float4 A = ab4[bin * 8 + e];
        float4 Bv = ab4[bin * 8 + e + 4];
        float4 I = im4[bin * 4 + e];
        int o = g * 17 + e * 4;
        float* sm = half ? sm2hi : sm2lo;
        float* si = half ? simhi : simlo;
        sm[o + 0] = A.x * A.x + Bv.x * Bv.x;
        sm[o + 1] = A.y * A.y + Bv.y * Bv.y;
        sm[o + 2] = A.z * A.z + Bv.z * Bv.z;
        sm[o + 3] = A.w * A.w + Bv.w * Bv.w;
        si[o + 0] = I.x; si[o + 1] = I.y; si[o + 2] = I.z; si[o + 3] = I.w;
    }
    __syncthreads();

    int k = k0 + tid;
    int m = 2048 - k;
    int rhi = 255 - tid;
    const float* mp = ws + OFF_MAXP + be * 4;
    float m2x = fmaxf(fmaxf(mp[0], mp[1]), fmaxf(mp[2], mp[3]));
    float rden = 1.0f / (sqrtf(m2x) + 1e-8f);
    const __half2* Eb = (const __half2*)(ws + OFF_E) + (size_t)be * 16 * 2049;
    __half2* Zb = (__half2*)(ws + OFF_Z) + (size_t)be * 16 * 2048;
    float2 evlo[16], evhi[16];
#pragma unroll
    for (int f = 0; f < 16; ++f) {
        evlo[f] = __half22float2(Eb[(size_t)f * 2049 + k]);
        evhi[f] = __half22float2(Eb[(size_t)f * 2049 + m]);
    }
    float ym = (k == 0) ? 0.0f : 1.0f;
    float s4, c4; __sincosf((float)k * (TWO_PI / 4096.0f), &s4, &c4);
    const float SCL = 1.0f / 2048.0f;
    float srl = 0.f, sil = 0.f, srh = 0.f, sih = 0.f;
#pragma unroll
    for (int f = 0; f < 16; ++f) {
        float mh = sqrtf(sm2lo[tid * 17 + f]) * rden;
        float ph = atan2f(simlo[tid * 17 + f], mh) * 3.14159265358979f;
        float sp, cp; __sincosf(ph, &sp, &cp);
        float Tr = mh * cp, Ti = mh * sp;
        sil *= ym;
        srl += evlo[f].x; sil += evlo[f].y;
        float nr = srl * Tr - sil * Ti;
        sil = srl * Ti + sil * Tr; srl = nr;
        float mh2 = sqrtf(sm2hi[rhi * 17 + f]) * rden;
        float ph2 = atan2f(simhi[rhi * 17 + f], mh2) * 3.14159265358979f;
        float sp2, cp2; __sincosf(ph2, &sp2, &cp2);
        float Tr2 = mh2 * cp2, Ti2 = mh2 * sp2;
        sih *= ym;
        srh += evhi[f].x; sih += evhi[f].y;
        float nr2 = srh * Tr2 - sih * Ti2;
        sih = srh * Ti2 + sih * Tr2; srh = nr2;
        __half2* Zf = Zb + (size_t)f * 2048;
        if (k == 0) {
            float y0 = srl * SCL, yn = srh * SCL;
            Zf[0] = __floats2half2_rn(0.5f * (y0 + yn), 0.5f * (y0 - yn));
        } else {
            float ykr = srl * SCL, yki = sil * SCL;
            float ymr = srh * SCL, ymi = sih * SCL;
            float er = 0.5f * (ykr + ymr), ei = 0.5f * (yki - ymi);
            float dr = ykr - ymr, di = yki + ymi;
            float orr = 0.5f * (dr * c4 - di * s4);
            float oi = 0.5f * (dr * s4 + di * c4);
            Zf[k] = __floats2half2_rn(er - oi, ei + orr);
            Zf[m] = __floats2half2_rn(er + oi, orr - ei);
        }
    }
    if (k0 == 0 && tid == 0) {   // bin 1024 (self-paired)
        float sr = 0.f, si = 0.f;
#pragma unroll
        for (int f = 0; f < 16; ++f) {
            float a = tfb[1024 * 32 + f];
            float b = tfb[1024 * 32 + 16 + f];
            float im = tfb[32784 + 1024 * 16 + f];
            float mh = sqrtf(a * a + b * b) * rden;
            float ph = atan2f(im, mh) * 3.14159265358979f;
            float sp, cp; __sincosf(ph, &sp, &cp);
            float Tr = mh * cp, Ti = mh * sp;
            float2 e = __half22float2(Eb[(size_t)f * 2049 + 1024]);
            sr += e.x; si += e.y;
            float nr = sr * Tr - si * Ti;
            si = sr * Ti + si * Tr; sr = nr;
            Zb[(size_t)f * 2048 + 1024] = __floats2half2_rn(sr * SCL, -si * SCL);
        }
    }
}

// ---- inverse FFT: 4 frames per block, packed half2 LDS, merged final radix-2
__global__ __launch_bounds__(1024, 8) void k_fft_inv(float* __restrict__ ws) {
    __shared__ unsigned B2[8192];   // 4 FFTs x 2048 packed half2 = 32 KB
    int tid = threadIdx.x;
    int be = blockIdx.x >> 2, fg = blockIdx.x & 3;
    const __half2* Zbase = (const __half2*)(ws + OFF_Z) + (size_t)(be * 16 + fg * 4) * 2048;
    {
        int n0 = tid * 2;
        int p0 = swz(permf(n0)), p1 = swz(permf(n0 + 1));
#pragma unroll
        for (int j4 = 0; j4 < 4; ++j4) {
            uint2 raw = ((const uint2*)(Zbase + (size_t)j4 * 2048))[tid];
            unsigned* bb = B2 + j4 * 2048;
            bb[p0] = raw.x;
            bb[p1] = raw.y;
        }
    }
    __syncthreads();
    STAGE4P(i_ * 4, 1, 0.0f);
    STAGE4P((i_ & 127) * 16 + (i_ >> 7), 4, (float)(i_ >> 7) * (TWO_PI / 16.0f));
    STAGE4P((i_ & 31) * 64 + (i_ >> 5), 16, (float)(i_ >> 5) * (TWO_PI / 64.0f));
    STAGE4P((i_ >> 6) * 256 + (i_ & 63), 64, (float)(i_ & 63) * (TWO_PI / 256.0f));
    STAGE4P((i_ >> 8) * 1024 + (i_ & 255), 256, (float)(i_ & 255) * (TWO_PI / 1024.0f));
    // merged radix-2 (h=1024) + F writeback
    {
        int sj = swz(tid), sjb = swz(tid + 1024);
        float s, c; __sincosf((float)tid * (TWO_PI / 2048.0f), &s, &c);
        __half2* Fbase = (__half2*)(ws + OFF_F) + (size_t)(be * 16 + fg * 4) * 2048;
#pragma unroll
        for (int j4 = 0; j4 < 4; ++j4) {
            unsigned* bb = B2 + j4 * 2048;
            float2 a = uph(bb[sj]);
            float2 b = uph(bb[sjb]);
            float tr = b.x * c - b.y * s, ti2 = b.x * s + b.y * c;
            __half2* Fg = Fbase + (size_t)j4 * 2048;
            Fg[tid] = __floats2half2_rn(a.x + tr, a.y + ti2);
            Fg[tid + 1024] = __floats2half2_rn(a.x - tr, a.y - ti2);
        }
    }
}

// ---- gather + fused overlap-add (F half in, f32 out)
__global__ __launch_bounds__(256) void k_segment(const float* __restrict__ ws,
                                                 const int* __restrict__ indices,
                                                 float* __restrict__ out) {
    __shared__ int ste[16];
    int tid = threadIdx.x;
    int b = blockIdx.y;
    if (tid < 16) ste[tid] = indices[b * 16 + tid] * 256;
    __syncthreads();
    int g = blockIdx.x * 256 + tid;
    int t = g << 2;
    const __half* F = (const __half*)(ws + OFF_F);
    float4 acc = make_float4(0.f, 0.f, 0.f, 0.f);
#pragma unroll
    for (int e = 0; e < 16; ++e) {
        int te = ste[e];
        if (t >= te) {
            int d = t - te;
            int j = d >> 11, r = d & 2047;
            size_t base = (size_t)(b * 16 + e) * 65536;
            uint2 raw = *(const uint2*)(F + base + j * 4096 + r);
            float2 a0 = __half22float2(*(const __half2*)&raw.x);
            float2 a1 = __half22float2(*(const __half2*)&raw.y);
            acc.x += a0.x; acc.y += a0.y; acc.z += a1.x; acc.w += a1.y;
            if (j >= 1) {
                uint2 rw2 = *(const uint2*)(F + base + (j - 1) * 4096 + 2048 + r);
                float2 b0 = __half22float2(*(const __half2*)&rw2.x);
                float2 b1 = __half22float2(*(const __half2*)&rw2.y);
                acc.x += b0.x; acc.y += b0.y; acc.z += b1.x; acc.w += b1.y;
            }
        }
    }
    ((float4*)out)[(size_t)b * 8192 + g] = acc;
}

extern "C" void kernel_launch(void* const* d_in, const int* in_sizes, int n_in,
                              void* d_out, int out_size, void* d_ws, size_t ws_size,
                              hipStream_t stream) {
    const float* env = (const float*)d_in[0];
    const float* tf = (const float*)d_in[1];
    const float* noise = (const float*)d_in[2];
    const int* indices = (const int*)d_in[3];
    float* ws = (float*)d_ws;
    float* out = (float*)d_out;

    k_fwd<<<dim3(512), dim3(1024), 0, stream>>>(env, noise, tf, ws);
    k_recur<<<dim3(4, 128), dim3(256), 0, stream>>>(tf, ws);
    k_fft_inv<<<dim3(512), dim3(1024), 0, stream>>>(ws);
    k_segment<<<dim3(32, 8), dim3(256), 0, stream>>>(ws, indices, out);
}